// Round 1
// baseline (86.670 us; speedup 1.0000x reference)
//
#include <hip/hip_runtime.h>
#include <hip/hip_bf16.h>

#define HID 768
#define NPAIR 32640   // 256*255/2

typedef short bf16x8 __attribute__((ext_vector_type(8)));
typedef unsigned short ushort8_t __attribute__((ext_vector_type(8)));
typedef float f32x4 __attribute__((ext_vector_type(4)));

// manual RNE f32 -> bf16 bits (no NaN inputs here)
__device__ __forceinline__ unsigned short f2bf(float x) {
    union { float f; unsigned int u; } v; v.f = x;
    unsigned int lsb = (v.u >> 16) & 1u;
    return (unsigned short)((v.u + 0x7fffu + lsb) >> 16);
}

// ---------------- cast feat f32 -> bf16 ----------------
__global__ void cast_feat_k(const float* __restrict__ in, unsigned short* __restrict__ out, int n4) {
    int i = blockIdx.x * blockDim.x + threadIdx.x;
    if (i < n4) {
        float4 f = reinterpret_cast<const float4*>(in)[i];
        ushort4 o;
        o.x = f2bf(f.x); o.y = f2bf(f.y); o.z = f2bf(f.z); o.w = f2bf(f.w);
        reinterpret_cast<ushort4*>(out)[i] = o;
    }
}

// ---------------- transpose + cast: in f32 [R][C] -> out bf16 [C][R] ----------------
__global__ void tcast_k(const float* __restrict__ in, unsigned short* __restrict__ out, int R, int C) {
    __shared__ float t[32][33];
    int c0 = blockIdx.x * 32, r0 = blockIdx.y * 32;
    int tx = threadIdx.x, ty = threadIdx.y; // 32 x 8
    for (int k = 0; k < 4; ++k)
        t[ty + 8*k][tx] = in[(size_t)(r0 + ty + 8*k) * C + c0 + tx];
    __syncthreads();
    for (int k = 0; k < 4; ++k)
        out[(size_t)(c0 + ty + 8*k) * R + r0 + tx] = f2bf(t[tx][ty + 8*k]);
}

// ---------------- AB = feat(bf16) @ W1x^T : M=256, N=1536, K=768, f32 out ----------------
// W1x bf16 [1536][768]: row n holds (n<768 ? W1[:,n] top-half : W1[768:, n-768] bottom-half)
__launch_bounds__(256, 2)
__global__ void ab_gemm_k(const unsigned short* __restrict__ F,
                          const unsigned short* __restrict__ W,
                          float* __restrict__ AB) {
    __shared__ unsigned short fl[64*72];
    __shared__ unsigned short wl[128*72];
    int tid = threadIdx.x;
    int lane = tid & 63, wid = tid >> 6;   // 4 waves
    int n0 = blockIdx.x * 128, m0 = blockIdx.y * 64;
    f32x4 acc[4][2] = {};
    for (int kk = 0; kk < HID; kk += 64) {
        __syncthreads();
        for (int s = 0; s < 2; ++s) {      // F tile 64x64
            int idx = tid + s*256;
            int r = idx >> 3, c8 = idx & 7;
            *(ushort8_t*)(fl + r*72 + c8*8) =
                *(const ushort8_t*)(F + (size_t)(m0 + r)*HID + kk + c8*8);
        }
        for (int s = 0; s < 4; ++s) {      // W tile 128x64
            int idx = tid + s*256;
            int r = idx >> 3, c8 = idx & 7;
            *(ushort8_t*)(wl + r*72 + c8*8) =
                *(const ushort8_t*)(W + (size_t)(n0 + r)*HID + kk + c8*8);
        }
        __syncthreads();
        for (int ks = 0; ks < 2; ++ks) {
            bf16x8 a[4], b[2];
            for (int fm = 0; fm < 4; ++fm)
                a[fm] = *(const bf16x8*)(fl + (fm*16 + (lane&15))*72 + ks*32 + (lane>>4)*8);
            for (int fn = 0; fn < 2; ++fn)
                b[fn] = *(const bf16x8*)(wl + (wid*32 + fn*16 + (lane&15))*72 + ks*32 + (lane>>4)*8);
            for (int fm = 0; fm < 4; ++fm)
                for (int fn = 0; fn < 2; ++fn)
                    acc[fm][fn] = __builtin_amdgcn_mfma_f32_16x16x32_bf16(a[fm], b[fn], acc[fm][fn], 0,0,0);
        }
    }
    for (int fm = 0; fm < 4; ++fm)
        for (int fn = 0; fn < 2; ++fn)
            for (int q = 0; q < 4; ++q) {
                int row = m0 + fm*16 + (lane>>4)*4 + q;
                int col = n0 + wid*32 + fn*16 + (lane&15);
                AB[(size_t)row*1536 + col] = acc[fm][fn][q];
            }
}

// ---------------- fused pair MLP: h1=relu(A[i]+B[j]+b1); h2=relu(h1@W2+b2); out=h2@W3+b3 ----
// grid 255 blocks x 128 pairs; 512 threads = 8 waves (2x4 for layer2)
__launch_bounds__(512, 2)
__global__ void fused_k(const float* __restrict__ AB,            // [256][1536] f32 (A | B)
                        const float* __restrict__ b1,            // [768]
                        const unsigned short* __restrict__ W2t,  // [384][768] bf16
                        const float* __restrict__ b2,            // [384]
                        const unsigned short* __restrict__ W3t,  // [128][384] bf16
                        const float* __restrict__ b3,            // [128]
                        float* __restrict__ out) {               // [32640][128] f32
    __shared__ alignas(16) char smem[119808];
    int* ri = (int*)smem;                                        // [128]
    int* rj = ri + 128;                                          // [128]
    unsigned short* h1 = (unsigned short*)(smem + 1024);         // [128][72] phase A
    unsigned short* w2 = (unsigned short*)(smem + 1024 + 18432); // [384][72] phase A
    unsigned short* h2 = (unsigned short*)(smem + 1024);         // [128][392] phase B (reuse)
    unsigned short* w3 = (unsigned short*)(smem + 101376);       // [128][72] phase B

    int tid = threadIdx.x;
    int lane = tid & 63, wid = tid >> 6;   // 8 waves
    int wr = wid >> 2, wc = wid & 3;       // 2 x 4 wave grid (rows x cols)
    int p0 = blockIdx.x * 128;

    if (tid < 128) {                       // pair index -> (i, j) map
        int p = p0 + tid;
        float s = sqrtf((float)(511*511 - 8*p));
        int i = (int)((511.0f - s) * 0.5f);
        if (i < 0) i = 0; if (i > 254) i = 254;
        while (i < 255 && (i+1)*255 - (i+1)*i/2 <= p) ++i;
        while (i > 0 && i*255 - i*(i-1)/2 > p) --i;
        int base = i*255 - i*(i-1)/2;
        ri[tid] = i;
        rj[tid] = i + 1 + (p - base);
    }

    f32x4 acc2[4][6] = {};
    int hr = tid >> 2;            // h1-gen: row 0..127
    int hc = (tid & 3) * 16;      // col chunk

    for (int kk = 0; kk < HID; kk += 64) {
        __syncthreads();
        {   // h1 tile gen: relu(A[i] + B[j] + b1) -> bf16 LDS [128][72-pitch]
            int i = ri[hr], j = rj[hr];
            const float4* pa  = (const float4*)(AB + (size_t)i*1536 + kk + hc);
            const float4* pb  = (const float4*)(AB + (size_t)j*1536 + 768 + kk + hc);
            const float4* pb1 = (const float4*)(b1 + kk + hc);
            unsigned short us[16];
            for (int u = 0; u < 4; ++u) {
                float4 a = pa[u], b = pb[u], c = pb1[u];
                us[u*4+0] = f2bf(fmaxf(a.x + b.x + c.x, 0.f));
                us[u*4+1] = f2bf(fmaxf(a.y + b.y + c.y, 0.f));
                us[u*4+2] = f2bf(fmaxf(a.z + b.z + c.z, 0.f));
                us[u*4+3] = f2bf(fmaxf(a.w + b.w + c.w, 0.f));
            }
            *(ushort8_t*)(h1 + hr*72 + hc)     = *(ushort8_t*)us;
            *(ushort8_t*)(h1 + hr*72 + hc + 8) = *(ushort8_t*)(us + 8);
        }
        for (int s = 0; s < 6; ++s) {   // W2t tile [384][64]
            int idx = tid + s*512;
            int r = idx >> 3, c8 = idx & 7;
            *(ushort8_t*)(w2 + r*72 + c8*8) =
                *(const ushort8_t*)(W2t + (size_t)r*768 + kk + c8*8);
        }
        __syncthreads();
        for (int ks = 0; ks < 2; ++ks) {
            bf16x8 a[4], b[6];
            for (int fm = 0; fm < 4; ++fm)
                a[fm] = *(const bf16x8*)(h1 + (wr*64 + fm*16 + (lane&15))*72 + ks*32 + (lane>>4)*8);
            for (int fn = 0; fn < 6; ++fn)
                b[fn] = *(const bf16x8*)(w2 + (wc*96 + fn*16 + (lane&15))*72 + ks*32 + (lane>>4)*8);
            for (int fm = 0; fm < 4; ++fm)
                for (int fn = 0; fn < 6; ++fn)
                    acc2[fm][fn] = __builtin_amdgcn_mfma_f32_16x16x32_bf16(a[fm], b[fn], acc2[fm][fn], 0,0,0);
        }
    }
    __syncthreads();
    // h2 = relu(acc2 + b2) -> bf16 LDS [128][392-pitch]
    for (int fn = 0; fn < 6; ++fn) {
        int col = wc*96 + fn*16 + (lane&15);
        float bb = b2[col];
        for (int fm = 0; fm < 4; ++fm)
            for (int q = 0; q < 4; ++q) {
                int row = wr*64 + fm*16 + (lane>>4)*4 + q;
                h2[row*392 + col] = f2bf(fmaxf(acc2[fm][fn][q] + bb, 0.f));
            }
    }
    __syncthreads();

    f32x4 acc3[8] = {};
    for (int kt = 0; kt < 6; ++kt) {
        for (int s = 0; s < 2; ++s) {   // W3t tile [128][64]
            int idx = tid + s*512;
            int r = idx >> 3, c8 = idx & 7;
            *(ushort8_t*)(w3 + r*72 + c8*8) =
                *(const ushort8_t*)(W3t + (size_t)r*384 + kt*64 + c8*8);
        }
        __syncthreads();
        for (int ks = 0; ks < 2; ++ks) {
            bf16x8 a = *(const bf16x8*)(h2 + (wid*16 + (lane&15))*392 + kt*64 + ks*32 + (lane>>4)*8);
            for (int fn = 0; fn < 8; ++fn) {
                bf16x8 b = *(const bf16x8*)(w3 + (fn*16 + (lane&15))*72 + ks*32 + (lane>>4)*8);
                acc3[fn] = __builtin_amdgcn_mfma_f32_16x16x32_bf16(a, b, acc3[fn], 0,0,0);
            }
        }
        __syncthreads();
    }
    for (int fn = 0; fn < 8; ++fn) {
        int col = fn*16 + (lane&15);
        float bb = b3[col];
        for (int q = 0; q < 4; ++q) {
            int row = p0 + wid*16 + (lane>>4)*4 + q;
            out[(size_t)row*128 + col] = acc3[fn][q] + bb;
        }
    }
}

extern "C" void kernel_launch(void* const* d_in, const int* in_sizes, int n_in,
                              void* d_out, int out_size, void* d_ws, size_t ws_size,
                              hipStream_t stream) {
    const float* feat = (const float*)d_in[0];  // [256][768]
    const float* W1   = (const float*)d_in[1];  // [1536][768]
    const float* b1   = (const float*)d_in[2];  // [768]
    const float* W2   = (const float*)d_in[3];  // [768][384]
    const float* b2   = (const float*)d_in[4];  // [384]
    const float* W3   = (const float*)d_in[5];  // [384][128]
    const float* b3   = (const float*)d_in[6];  // [128]
    float* out = (float*)d_out;

    char* ws = (char*)d_ws;
    unsigned short* feat_bf = (unsigned short*)(ws + 0);        // 256*768*2   = 393216
    unsigned short* W1x     = (unsigned short*)(ws + 393216);   // 1536*768*2  = 2359296
    unsigned short* W2t     = (unsigned short*)(ws + 2752512);  // 384*768*2   = 589824
    unsigned short* W3t     = (unsigned short*)(ws + 3342336);  // 128*384*2   = 98304
    float*          AB      = (float*)        (ws + 3440640);   // 256*1536*4  = 1572864
    // total ws use: 5013504 bytes

    cast_feat_k<<<192, 256, 0, stream>>>(feat, feat_bf, 49152);
    // W1 top half  [768][768] -> W1x rows 0..767 ;  bottom half -> rows 768..1535
    tcast_k<<<dim3(24,24), dim3(32,8), 0, stream>>>(W1,            W1x,            768, 768);
    tcast_k<<<dim3(24,24), dim3(32,8), 0, stream>>>(W1 + 768*768,  W1x + 768*768,  768, 768);
    tcast_k<<<dim3(12,24), dim3(32,8), 0, stream>>>(W2, W2t, 768, 384);
    tcast_k<<<dim3(4,12),  dim3(32,8), 0, stream>>>(W3, W3t, 384, 128);
    ab_gemm_k<<<dim3(12,4), 256, 0, stream>>>(feat_bf, W1x, AB);
    fused_k<<<dim3(255), 512, 0, stream>>>(AB, b1, W2t, b2, W3t, b3, out);
}

// Round 2
// 75.112 us; speedup vs baseline: 1.1539x; 1.1539x over previous
//
#include <hip/hip_runtime.h>
#include <hip/hip_bf16.h>
#include <stdint.h>

#define HID 768

typedef short bf16x8 __attribute__((ext_vector_type(8)));
typedef unsigned short ushort8_t __attribute__((ext_vector_type(8)));
typedef float f32x4 __attribute__((ext_vector_type(4)));

// manual RNE f32 -> bf16 bits (no NaN inputs here)
__device__ __forceinline__ unsigned short f2bf(float x) {
    union { float f; unsigned int u; } v; v.f = x;
    unsigned int lsb = (v.u >> 16) & 1u;
    return (unsigned short)((v.u + 0x7fffu + lsb) >> 16);
}

// async global->LDS, 16B per lane; lds dest = wave-uniform base + lane*16
__device__ __forceinline__ void gload_lds16(const void* g, void* l) {
    __builtin_amdgcn_global_load_lds(
        (const __attribute__((address_space(1))) unsigned int*)g,
        (__attribute__((address_space(3))) unsigned int*)l, 16, 0, 0);
}

// ---------------- merged transpose+cast: 4 regions, f32 [R][C] -> bf16 [C][R] ----
__global__ void prep_k(const float* __restrict__ W1,
                       const float* __restrict__ W2,
                       const float* __restrict__ W3,
                       unsigned short* __restrict__ W1x,
                       unsigned short* __restrict__ W2t,
                       unsigned short* __restrict__ W3t) {
    __shared__ float t[32][33];
    int b = blockIdx.x;
    const float* in; unsigned short* op; int R, C, bx, by;
    if (b < 576)       { in = W1;           op = W1x;           R = 768; C = 768; bx = b % 24;          by = b / 24; }
    else if (b < 1152) { in = W1 + 768*768; op = W1x + 768*768; R = 768; C = 768; bx = (b-576) % 24;    by = (b-576) / 24; }
    else if (b < 1440) { in = W2;           op = W2t;           R = 768; C = 384; bx = (b-1152) % 12;   by = (b-1152) / 12; }
    else               { in = W3;           op = W3t;           R = 384; C = 128; bx = (b-1440) % 4;    by = (b-1440) / 4; }
    int c0 = bx * 32, r0 = by * 32;
    int tx = threadIdx.x, ty = threadIdx.y;   // 32 x 8
    #pragma unroll
    for (int k = 0; k < 4; ++k)
        t[ty + 8*k][tx] = in[(size_t)(r0 + ty + 8*k) * C + c0 + tx];
    __syncthreads();
    #pragma unroll
    for (int k = 0; k < 4; ++k)
        op[(size_t)(c0 + ty + 8*k) * R + r0 + tx] = f2bf(t[tx][ty + 8*k]);
}

// ---------------- AB = feat @ W1x^T (+b1 on A half) : M=256, N=1536, K=768 ------
// feat f32 [256][768] cast to bf16 during staging; W1x bf16 [1536][768]
__launch_bounds__(256, 2)
__global__ void ab_gemm_k(const float* __restrict__ F,
                          const unsigned short* __restrict__ W,
                          const float* __restrict__ b1,
                          float* __restrict__ AB) {
    __shared__ unsigned short fl[64*72];
    __shared__ unsigned short wl[128*72];
    int tid = threadIdx.x;
    int lane = tid & 63, wid = tid >> 6;   // 4 waves
    int n0 = blockIdx.x * 128, m0 = blockIdx.y * 64;
    f32x4 acc[4][2] = {};
    for (int kk = 0; kk < HID; kk += 64) {
        __syncthreads();
        #pragma unroll
        for (int s = 0; s < 2; ++s) {      // F tile 64x64, f32 -> bf16
            int idx = tid + s*256;
            int r = idx >> 3, c8 = idx & 7;
            const float4* src = (const float4*)(F + (size_t)(m0 + r)*HID + kk + c8*8);
            float4 f0 = src[0], f1 = src[1];
            unsigned short us[8] = { f2bf(f0.x), f2bf(f0.y), f2bf(f0.z), f2bf(f0.w),
                                     f2bf(f1.x), f2bf(f1.y), f2bf(f1.z), f2bf(f1.w) };
            *(ushort8_t*)(fl + r*72 + c8*8) = *(ushort8_t*)us;
        }
        #pragma unroll
        for (int s = 0; s < 4; ++s) {      // W tile 128x64
            int idx = tid + s*256;
            int r = idx >> 3, c8 = idx & 7;
            *(ushort8_t*)(wl + r*72 + c8*8) =
                *(const ushort8_t*)(W + (size_t)(n0 + r)*HID + kk + c8*8);
        }
        __syncthreads();
        #pragma unroll
        for (int ks = 0; ks < 2; ++ks) {
            bf16x8 a[4], b[2];
            #pragma unroll
            for (int fm = 0; fm < 4; ++fm)
                a[fm] = *(const bf16x8*)(fl + (fm*16 + (lane&15))*72 + ks*32 + (lane>>4)*8);
            #pragma unroll
            for (int fn = 0; fn < 2; ++fn)
                b[fn] = *(const bf16x8*)(wl + (wid*32 + fn*16 + (lane&15))*72 + ks*32 + (lane>>4)*8);
            #pragma unroll
            for (int fm = 0; fm < 4; ++fm)
                #pragma unroll
                for (int fn = 0; fn < 2; ++fn)
                    acc[fm][fn] = __builtin_amdgcn_mfma_f32_16x16x32_bf16(a[fm], b[fn], acc[fm][fn], 0,0,0);
        }
    }
    #pragma unroll
    for (int fm = 0; fm < 4; ++fm)
        #pragma unroll
        for (int fn = 0; fn < 2; ++fn)
            #pragma unroll
            for (int q = 0; q < 4; ++q) {
                int row = m0 + fm*16 + (lane>>4)*4 + q;
                int col = n0 + wid*32 + fn*16 + (lane&15);
                float bias = (col < 768) ? b1[col] : 0.0f;   // fold b1 into A half
                AB[(size_t)row*1536 + col] = acc[fm][fn][q] + bias;
            }
}

// ---------------- fused pair MLP, double-buffered pipeline ----------------------
// h1 = relu(A[i]+B[j]) (b1 pre-folded); h2 = relu(h1@W2+b2); out = h2@W3+b3
// 255 blocks x 128 pairs, 512 thr = 8 waves (2x4)
__launch_bounds__(512, 2)
__global__ void fused_k(const float* __restrict__ AB,            // [256][1536] f32
                        const unsigned short* __restrict__ W2t,  // [384][768] bf16
                        const float* __restrict__ b2,            // [384]
                        const unsigned short* __restrict__ W3t,  // [128][384] bf16
                        const float* __restrict__ b3,            // [128]
                        float* __restrict__ out) {               // [32640][128] f32
    __shared__ alignas(1024) char smem[135168];
    unsigned short* h1b = (unsigned short*)(smem);            // 2 x [128][72]   (36,864 B)
    unsigned short* w2b = (unsigned short*)(smem + 36864);    // 2 x [384][64] swizzled (98,304 B)
    unsigned short* h2  = (unsigned short*)(smem);            // [128][392] phase B (100,352 B)
    unsigned short* w3b = (unsigned short*)(smem + 100352);   // 2 x [128][64] swizzled (32,768 B)

    int tid = threadIdx.x;
    int lane = tid & 63, wid = tid >> 6;   // 8 waves
    int wr = wid >> 2, wc = wid & 3;       // 2 x 4 wave grid
    int p0 = blockIdx.x * 128;

    // per-thread pair indices for my h1-gen row
    int hr = tid >> 2;                     // 0..127
    int hc = (tid & 3) * 16;               // col chunk within 64
    int p = p0 + hr;
    float sdisc = sqrtf((float)(511*511 - 8*p));
    int i_me = (int)((511.0f - sdisc) * 0.5f);
    if (i_me < 0) i_me = 0; if (i_me > 254) i_me = 254;
    while (i_me < 255 && (i_me+1)*255 - (i_me+1)*i_me/2 <= p) ++i_me;
    while (i_me > 0 && i_me*255 - i_me*(i_me-1)/2 > p) --i_me;
    int j_me = i_me + 1 + (p - (i_me*255 - i_me*(i_me-1)/2));

    float4 ra[4], rb[4];

    // ---- prologue: stage step 0 (w2 buf0 async; h1 buf0 via regs)
    #pragma unroll
    for (int s = 0; s < 6; ++s) {
        int chunk = wid*6 + s;                 // 48 chunks of 8 rows
        int row = chunk*8 + (lane>>3);
        int cg = (lane&7) ^ (row&7);           // pre-swizzled global source
        gload_lds16(W2t + (size_t)row*HID + cg*8, (char*)w2b + chunk*1024);
    }
    {
        const float4* pa = (const float4*)(AB + (size_t)i_me*1536 + hc);
        const float4* pb = (const float4*)(AB + (size_t)j_me*1536 + 768 + hc);
        #pragma unroll
        for (int u = 0; u < 4; ++u) { ra[u] = pa[u]; rb[u] = pb[u]; }
        unsigned short us[16];
        #pragma unroll
        for (int u = 0; u < 4; ++u) {
            us[u*4+0] = f2bf(fmaxf(ra[u].x + rb[u].x, 0.f));
            us[u*4+1] = f2bf(fmaxf(ra[u].y + rb[u].y, 0.f));
            us[u*4+2] = f2bf(fmaxf(ra[u].z + rb[u].z, 0.f));
            us[u*4+3] = f2bf(fmaxf(ra[u].w + rb[u].w, 0.f));
        }
        *(ushort8_t*)(h1b + hr*72 + hc)     = *(ushort8_t*)(us);
        *(ushort8_t*)(h1b + hr*72 + hc + 8) = *(ushort8_t*)(us + 8);
    }
    __syncthreads();

    f32x4 acc2[4][6] = {};
    for (int t = 0; t < 12; ++t) {
        int cur = t & 1;
        unsigned short* h1c = h1b + cur * (128*72);
        unsigned short* w2c = w2b + cur * (384*64);
        if (t < 11) {                          // issue next-step loads BEFORE compute
            int kk = (t+1) * 64;
            unsigned short* w2n = w2b + (cur^1) * (384*64);
            #pragma unroll
            for (int s = 0; s < 6; ++s) {
                int chunk = wid*6 + s;
                int row = chunk*8 + (lane>>3);
                int cg = (lane&7) ^ (row&7);
                gload_lds16(W2t + (size_t)row*HID + kk + cg*8, (char*)w2n + chunk*1024);
            }
            const float4* pa = (const float4*)(AB + (size_t)i_me*1536 + kk + hc);
            const float4* pb = (const float4*)(AB + (size_t)j_me*1536 + 768 + kk + hc);
            #pragma unroll
            for (int u = 0; u < 4; ++u) { ra[u] = pa[u]; rb[u] = pb[u]; }
        }
        __builtin_amdgcn_s_setprio(1);
        #pragma unroll
        for (int ks = 0; ks < 2; ++ks) {
            bf16x8 a[4], b[6];
            #pragma unroll
            for (int fm = 0; fm < 4; ++fm)
                a[fm] = *(const bf16x8*)(h1c + (wr*64 + fm*16 + (lane&15))*72 + ks*32 + (lane>>4)*8);
            #pragma unroll
            for (int fn = 0; fn < 6; ++fn) {
                int n = wc*96 + fn*16 + (lane&15);
                int g = ks*4 + (lane>>4);
                b[fn] = *(const bf16x8*)(w2c + n*64 + ((g ^ (n&7)) * 8));
            }
            #pragma unroll
            for (int fm = 0; fm < 4; ++fm)
                #pragma unroll
                for (int fn = 0; fn < 6; ++fn)
                    acc2[fm][fn] = __builtin_amdgcn_mfma_f32_16x16x32_bf16(a[fm], b[fn], acc2[fm][fn], 0,0,0);
        }
        __builtin_amdgcn_s_setprio(0);
        if (t < 11) {                          // consume prefetched AB -> h1[next]
            unsigned short* h1n = h1b + (cur^1) * (128*72);
            unsigned short us[16];
            #pragma unroll
            for (int u = 0; u < 4; ++u) {
                us[u*4+0] = f2bf(fmaxf(ra[u].x + rb[u].x, 0.f));
                us[u*4+1] = f2bf(fmaxf(ra[u].y + rb[u].y, 0.f));
                us[u*4+2] = f2bf(fmaxf(ra[u].z + rb[u].z, 0.f));
                us[u*4+3] = f2bf(fmaxf(ra[u].w + rb[u].w, 0.f));
            }
            *(ushort8_t*)(h1n + hr*72 + hc)     = *(ushort8_t*)(us);
            *(ushort8_t*)(h1n + hr*72 + hc + 8) = *(ushort8_t*)(us + 8);
        }
        __syncthreads();
    }

    // h2 = relu(acc2 + b2) -> LDS [128][392] (2-way write conflicts only)
    #pragma unroll
    for (int fn = 0; fn < 6; ++fn) {
        int col = wc*96 + fn*16 + (lane&15);
        float bb = b2[col];
        #pragma unroll
        for (int fm = 0; fm < 4; ++fm)
            #pragma unroll
            for (int q = 0; q < 4; ++q) {
                int row = wr*64 + fm*16 + (lane>>4)*4 + q;
                h2[row*392 + col] = f2bf(fmaxf(acc2[fm][fn][q] + bb, 0.f));
            }
    }
    #pragma unroll
    for (int s = 0; s < 2; ++s) {              // stage w3 kt=0
        int chunk = wid*2 + s;
        int row = chunk*8 + (lane>>3);
        int cg = (lane&7) ^ (row&7);
        gload_lds16(W3t + (size_t)row*384 + cg*8, (char*)w3b + chunk*1024);
    }
    __syncthreads();

    f32x4 acc3[8] = {};
    for (int kt = 0; kt < 6; ++kt) {
        int cur = kt & 1;
        unsigned short* w3c = w3b + cur * (128*64);
        if (kt < 5) {
            unsigned short* w3n = w3b + (cur^1) * (128*64);
            #pragma unroll
            for (int s = 0; s < 2; ++s) {
                int chunk = wid*2 + s;
                int row = chunk*8 + (lane>>3);
                int cg = (lane&7) ^ (row&7);
                gload_lds16(W3t + (size_t)row*384 + (kt+1)*64 + cg*8, (char*)w3n + chunk*1024);
            }
        }
        __builtin_amdgcn_s_setprio(1);
        #pragma unroll
        for (int ks = 0; ks < 2; ++ks) {
            bf16x8 a = *(const bf16x8*)(h2 + (wid*16 + (lane&15))*392 + kt*64 + ks*32 + (lane>>4)*8);
            #pragma unroll
            for (int fn = 0; fn < 8; ++fn) {
                int n = fn*16 + (lane&15);
                int g = ks*4 + (lane>>4);
                bf16x8 b = *(const bf16x8*)(w3c + n*64 + ((g ^ (n&7)) * 8));
                acc3[fn] = __builtin_amdgcn_mfma_f32_16x16x32_bf16(a, b, acc3[fn], 0,0,0);
            }
        }
        __builtin_amdgcn_s_setprio(0);
        __syncthreads();
    }
    #pragma unroll
    for (int fn = 0; fn < 8; ++fn) {
        int col = fn*16 + (lane&15);
        float bb = b3[col];
        #pragma unroll
        for (int q = 0; q < 4; ++q) {
            int row = p0 + wid*16 + (lane>>4)*4 + q;
            out[(size_t)row*128 + col] = acc3[fn][q] + bb;
        }
    }
}

extern "C" void kernel_launch(void* const* d_in, const int* in_sizes, int n_in,
                              void* d_out, int out_size, void* d_ws, size_t ws_size,
                              hipStream_t stream) {
    const float* feat = (const float*)d_in[0];  // [256][768]
    const float* W1   = (const float*)d_in[1];  // [1536][768]
    const float* b1   = (const float*)d_in[2];  // [768]
    const float* W2   = (const float*)d_in[3];  // [768][384]
    const float* b2   = (const float*)d_in[4];  // [384]
    const float* W3   = (const float*)d_in[5];  // [384][128]
    const float* b3   = (const float*)d_in[6];  // [128]
    float* out = (float*)d_out;

    char* ws = (char*)d_ws;
    unsigned short* W1x = (unsigned short*)(ws + 0);        // 1536*768*2 = 2,359,296
    unsigned short* W2t = (unsigned short*)(ws + 2359296);  // 384*768*2  =   589,824
    unsigned short* W3t = (unsigned short*)(ws + 2949120);  // 128*384*2  =    98,304
    float*          AB  = (float*)        (ws + 3047424);   // 256*1536*4 = 1,572,864
    // total ws use: 4,620,288 bytes

    prep_k<<<1488, dim3(32,8), 0, stream>>>(W1, W2, W3, W1x, W2t, W3t);
    ab_gemm_k<<<dim3(12,4), 256, 0, stream>>>(feat, W1x, b1, AB);
    fused_k<<<255, 512, 0, stream>>>(AB, W2t, b2, W3t, b3, out);
}

// Round 3
// 55.672 us; speedup vs baseline: 1.5568x; 1.3492x over previous
//
#include <hip/hip_runtime.h>
#include <hip/hip_bf16.h>
#include <stdint.h>

#define HID 768

typedef short bf16x8 __attribute__((ext_vector_type(8)));
typedef unsigned short ushort8_t __attribute__((ext_vector_type(8)));
typedef float f32x4 __attribute__((ext_vector_type(4)));

// packed f32x2 -> bf16x2 (compiler emits v_cvt_pk_bf16_f32)
__device__ __forceinline__ unsigned int pack2bf(float x, float y) {
    __hip_bfloat162 h = __float22bfloat162_rn(make_float2(x, y));
    return *reinterpret_cast<unsigned int*>(&h);
}
__device__ __forceinline__ unsigned short f2bf1(float x) {
    __hip_bfloat16 h = __float2bfloat16(x);
    return *reinterpret_cast<unsigned short*>(&h);
}

// async global->LDS, 16B per lane; lds dest = wave-uniform base + lane*16
__device__ __forceinline__ void gload_lds16(const void* g, void* l) {
    __builtin_amdgcn_global_load_lds(
        (const __attribute__((address_space(1))) unsigned int*)g,
        (__attribute__((address_space(3))) unsigned int*)l, 16, 0, 0);
}

// ---------------- merged transpose+cast: 4 regions, f32 [R][C] -> bf16 [C][R] ----
__global__ void prep_k(const float* __restrict__ W1,
                       const float* __restrict__ W2,
                       const float* __restrict__ W3,
                       unsigned short* __restrict__ W1x,
                       unsigned short* __restrict__ W2t,
                       unsigned short* __restrict__ W3t) {
    __shared__ float t[32][33];
    int b = blockIdx.x;
    const float* in; unsigned short* op; int R, C, bx, by;
    if (b < 576)       { in = W1;           op = W1x;           R = 768; C = 768; bx = b % 24;        by = b / 24; }
    else if (b < 1152) { in = W1 + 768*768; op = W1x + 768*768; R = 768; C = 768; bx = (b-576) % 24;  by = (b-576) / 24; }
    else if (b < 1440) { in = W2;           op = W2t;           R = 768; C = 384; bx = (b-1152) % 12; by = (b-1152) / 12; }
    else               { in = W3;           op = W3t;           R = 384; C = 128; bx = (b-1440) % 4;  by = (b-1440) / 4; }
    int c0 = bx * 32, r0 = by * 32;
    int tx = threadIdx.x, ty = threadIdx.y;   // 32 x 8
    #pragma unroll
    for (int k = 0; k < 4; ++k)
        t[ty + 8*k][tx] = in[(size_t)(r0 + ty + 8*k) * C + c0 + tx];
    __syncthreads();
    #pragma unroll
    for (int k = 0; k < 4; ++k)
        op[(size_t)(c0 + ty + 8*k) * R + r0 + tx] = f2bf1(t[tx][ty + 8*k]);
}

// ---------------- AB = feat @ W1x^T (+b1 on A half) : M=256, N=1536, K=768 ------
// pipelined: gload_lds dbuf for W (swizzled), reg-prefetch + write-late for F
__launch_bounds__(256, 2)
__global__ void ab_gemm_k(const float* __restrict__ F,
                          const unsigned short* __restrict__ W,
                          const float* __restrict__ b1,
                          float* __restrict__ AB) {
    __shared__ alignas(1024) unsigned short fl[2][64*72];   // 18,432 B
    __shared__ alignas(1024) unsigned short wl[2][128*64];  // 32,768 B (swizzled)
    int tid = threadIdx.x;
    int lane = tid & 63, wid = tid >> 6;   // 4 waves
    int n0 = blockIdx.x * 128, m0 = blockIdx.y * 64;
    f32x4 acc[4][2] = {};
    float4 rf[2][2];

    // prologue: stage step 0
    #pragma unroll
    for (int s = 0; s < 4; ++s) {          // W tile 128x64 -> 16 chunks of 1024B
        int chunk = wid*4 + s;
        int row = chunk*8 + (lane>>3);
        int cg = (lane&7) ^ (row&7);
        gload_lds16(W + (size_t)(n0 + row)*HID + cg*8, (char*)wl[0] + chunk*1024);
    }
    #pragma unroll
    for (int s = 0; s < 2; ++s) {          // F tile 64x64 f32
        int idx = tid + s*256;
        int r = idx >> 3, c8 = idx & 7;
        const float4* src = (const float4*)(F + (size_t)(m0 + r)*HID + c8*8);
        rf[s][0] = src[0]; rf[s][1] = src[1];
    }
    #pragma unroll
    for (int s = 0; s < 2; ++s) {
        int idx = tid + s*256;
        int r = idx >> 3, c8 = idx & 7;
        unsigned int us32[4] = { pack2bf(rf[s][0].x, rf[s][0].y), pack2bf(rf[s][0].z, rf[s][0].w),
                                 pack2bf(rf[s][1].x, rf[s][1].y), pack2bf(rf[s][1].z, rf[s][1].w) };
        *(ushort8_t*)(fl[0] + r*72 + c8*8) = *(ushort8_t*)us32;
    }
    __syncthreads();

    for (int t = 0; t < 12; ++t) {
        int cur = t & 1;
        if (t < 11) {                      // issue next-step loads
            int kk = (t+1) * 64;
            #pragma unroll
            for (int s = 0; s < 4; ++s) {
                int chunk = wid*4 + s;
                int row = chunk*8 + (lane>>3);
                int cg = (lane&7) ^ (row&7);
                gload_lds16(W + (size_t)(n0 + row)*HID + kk + cg*8, (char*)wl[cur^1] + chunk*1024);
            }
            #pragma unroll
            for (int s = 0; s < 2; ++s) {
                int idx = tid + s*256;
                int r = idx >> 3, c8 = idx & 7;
                const float4* src = (const float4*)(F + (size_t)(m0 + r)*HID + kk + c8*8);
                rf[s][0] = src[0]; rf[s][1] = src[1];
            }
        }
        __builtin_amdgcn_s_setprio(1);
        #pragma unroll
        for (int ks = 0; ks < 2; ++ks) {
            bf16x8 a[4], b[2];
            #pragma unroll
            for (int fm = 0; fm < 4; ++fm)
                a[fm] = *(const bf16x8*)(fl[cur] + (fm*16 + (lane&15))*72 + ks*32 + (lane>>4)*8);
            #pragma unroll
            for (int fn = 0; fn < 2; ++fn) {
                int n = wid*32 + fn*16 + (lane&15);
                int g = ks*4 + (lane>>4);
                b[fn] = *(const bf16x8*)(wl[cur] + n*64 + ((g ^ (n&7)) * 8));
            }
            #pragma unroll
            for (int fm = 0; fm < 4; ++fm)
                #pragma unroll
                for (int fn = 0; fn < 2; ++fn)
                    acc[fm][fn] = __builtin_amdgcn_mfma_f32_16x16x32_bf16(a[fm], b[fn], acc[fm][fn], 0,0,0);
        }
        __builtin_amdgcn_s_setprio(0);
        if (t < 11) {                      // write-late F -> fl[next]
            #pragma unroll
            for (int s = 0; s < 2; ++s) {
                int idx = tid + s*256;
                int r = idx >> 3, c8 = idx & 7;
                unsigned int us32[4] = { pack2bf(rf[s][0].x, rf[s][0].y), pack2bf(rf[s][0].z, rf[s][0].w),
                                         pack2bf(rf[s][1].x, rf[s][1].y), pack2bf(rf[s][1].z, rf[s][1].w) };
                *(ushort8_t*)(fl[cur^1] + r*72 + c8*8) = *(ushort8_t*)us32;
            }
        }
        __syncthreads();
    }
    #pragma unroll
    for (int fm = 0; fm < 4; ++fm)
        #pragma unroll
        for (int fn = 0; fn < 2; ++fn)
            #pragma unroll
            for (int q = 0; q < 4; ++q) {
                int row = m0 + fm*16 + (lane>>4)*4 + q;
                int col = n0 + wid*32 + fn*16 + (lane&15);
                float bias = (col < 768) ? b1[col] : 0.0f;   // fold b1 into A half
                AB[(size_t)row*1536 + col] = acc[fm][fn][q] + bias;
            }
}

// ---------------- fused pair MLP, 16 waves (4x4), double-buffered ---------------
__launch_bounds__(1024)
__global__ void fused_k(const float* __restrict__ AB,            // [256][1536] f32
                        const unsigned short* __restrict__ W2t,  // [384][768] bf16
                        const float* __restrict__ b2,            // [384]
                        const unsigned short* __restrict__ W3t,  // [128][384] bf16
                        const float* __restrict__ b3,            // [128]
                        float* __restrict__ out) {               // [32640][128] f32
    __shared__ alignas(1024) char smem[135168];
    unsigned short* h1b = (unsigned short*)(smem);            // 2 x [128][72]   (36,864 B)
    unsigned short* w2b = (unsigned short*)(smem + 36864);    // 2 x [384][64] swizzled (98,304 B)
    unsigned short* h2  = (unsigned short*)(smem);            // [128][392] phase B (100,352 B)
    unsigned short* w3b = (unsigned short*)(smem + 100352);   // 2 x [128][64] swizzled (32,768 B)

    int tid = threadIdx.x;
    int lane = tid & 63, wid = tid >> 6;   // 16 waves
    int wr = wid >> 2, wc = wid & 3;       // 4 x 4 wave grid (rows x cols)
    int p0 = blockIdx.x * 128;

    // per-thread pair indices for my h1-gen row (8 threads per row)
    int hr = tid >> 3;                     // 0..127
    int hc = (tid & 7) * 8;                // col chunk within 64
    int p = p0 + hr;
    float sdisc = sqrtf((float)(511*511 - 8*p));
    int i_me = (int)((511.0f - sdisc) * 0.5f);
    if (i_me < 0) i_me = 0; if (i_me > 254) i_me = 254;
    while (i_me < 255 && (i_me+1)*255 - (i_me+1)*i_me/2 <= p) ++i_me;
    while (i_me > 0 && i_me*255 - i_me*(i_me-1)/2 > p) --i_me;
    int j_me = i_me + 1 + (p - (i_me*255 - i_me*(i_me-1)/2));

    float4 ra[2], rb[2];

    // ---- prologue: stage step 0
    #pragma unroll
    for (int s = 0; s < 3; ++s) {
        int chunk = wid*3 + s;                 // 48 chunks of 1024B
        int row = chunk*8 + (lane>>3);
        int cg = (lane&7) ^ (row&7);
        gload_lds16(W2t + (size_t)row*HID + cg*8, (char*)w2b + chunk*1024);
    }
    {
        const float4* pa = (const float4*)(AB + (size_t)i_me*1536 + hc);
        const float4* pb = (const float4*)(AB + (size_t)j_me*1536 + 768 + hc);
        ra[0] = pa[0]; ra[1] = pa[1]; rb[0] = pb[0]; rb[1] = pb[1];
        unsigned int us32[4];
        #pragma unroll
        for (int u = 0; u < 2; ++u) {
            us32[u*2+0] = pack2bf(fmaxf(ra[u].x + rb[u].x, 0.f), fmaxf(ra[u].y + rb[u].y, 0.f));
            us32[u*2+1] = pack2bf(fmaxf(ra[u].z + rb[u].z, 0.f), fmaxf(ra[u].w + rb[u].w, 0.f));
        }
        *(ushort8_t*)(h1b + hr*72 + hc) = *(ushort8_t*)us32;
    }
    __syncthreads();

    f32x4 acc2[2][6] = {};
    for (int t = 0; t < 12; ++t) {
        int cur = t & 1;
        unsigned short* h1c = h1b + cur * (128*72);
        unsigned short* w2c = w2b + cur * (384*64);
        if (t < 11) {                          // issue next-step loads BEFORE compute
            int kk = (t+1) * 64;
            unsigned short* w2n = w2b + (cur^1) * (384*64);
            #pragma unroll
            for (int s = 0; s < 3; ++s) {
                int chunk = wid*3 + s;
                int row = chunk*8 + (lane>>3);
                int cg = (lane&7) ^ (row&7);
                gload_lds16(W2t + (size_t)row*HID + kk + cg*8, (char*)w2n + chunk*1024);
            }
            const float4* pa = (const float4*)(AB + (size_t)i_me*1536 + kk + hc);
            const float4* pb = (const float4*)(AB + (size_t)j_me*1536 + 768 + kk + hc);
            ra[0] = pa[0]; ra[1] = pa[1]; rb[0] = pb[0]; rb[1] = pb[1];
        }
        __builtin_amdgcn_s_setprio(1);
        #pragma unroll
        for (int ks = 0; ks < 2; ++ks) {
            bf16x8 a[2], b[6];
            #pragma unroll
            for (int fm = 0; fm < 2; ++fm)
                a[fm] = *(const bf16x8*)(h1c + (wr*32 + fm*16 + (lane&15))*72 + ks*32 + (lane>>4)*8);
            #pragma unroll
            for (int fn = 0; fn < 6; ++fn) {
                int n = wc*96 + fn*16 + (lane&15);
                int g = ks*4 + (lane>>4);
                b[fn] = *(const bf16x8*)(w2c + n*64 + ((g ^ (n&7)) * 8));
            }
            #pragma unroll
            for (int fm = 0; fm < 2; ++fm)
                #pragma unroll
                for (int fn = 0; fn < 6; ++fn)
                    acc2[fm][fn] = __builtin_amdgcn_mfma_f32_16x16x32_bf16(a[fm], b[fn], acc2[fm][fn], 0,0,0);
        }
        __builtin_amdgcn_s_setprio(0);
        if (t < 11) {                          // consume prefetched AB -> h1[next]
            unsigned short* h1n = h1b + (cur^1) * (128*72);
            unsigned int us32[4];
            #pragma unroll
            for (int u = 0; u < 2; ++u) {
                us32[u*2+0] = pack2bf(fmaxf(ra[u].x + rb[u].x, 0.f), fmaxf(ra[u].y + rb[u].y, 0.f));
                us32[u*2+1] = pack2bf(fmaxf(ra[u].z + rb[u].z, 0.f), fmaxf(ra[u].w + rb[u].w, 0.f));
            }
            *(ushort8_t*)(h1n + hr*72 + hc) = *(ushort8_t*)us32;
        }
        __syncthreads();
    }

    // h2 = relu(acc2 + b2) -> LDS [128][392]
    #pragma unroll
    for (int fn = 0; fn < 6; ++fn) {
        int col = wc*96 + fn*16 + (lane&15);
        float bb = b2[col];
        #pragma unroll
        for (int fm = 0; fm < 2; ++fm)
            #pragma unroll
            for (int q = 0; q < 4; ++q) {
                int row = wr*32 + fm*16 + (lane>>4)*4 + q;
                h2[row*392 + col] = f2bf1(fmaxf(acc2[fm][fn][q] + bb, 0.f));
            }
    }
    {   // stage w3 kt=0 (16 chunks, 1 per wave)
        int chunk = wid;
        int row = chunk*8 + (lane>>3);
        int cg = (lane&7) ^ (row&7);
        gload_lds16(W3t + (size_t)row*384 + cg*8, (char*)w3b + chunk*1024);
    }
    __syncthreads();

    // phase B: wave w -> rows (w&7)*16, col-half (w>>3)*64
    int rg = wid & 7, ch = wid >> 3;
    f32x4 acc3[4] = {};
    for (int kt = 0; kt < 6; ++kt) {
        int cur = kt & 1;
        unsigned short* w3c = w3b + cur * (128*64);
        if (kt < 5) {
            unsigned short* w3n = w3b + (cur^1) * (128*64);
            int chunk = wid;
            int row = chunk*8 + (lane>>3);
            int cg = (lane&7) ^ (row&7);
            gload_lds16(W3t + (size_t)row*384 + (kt+1)*64 + cg*8, (char*)w3n + chunk*1024);
        }
        __builtin_amdgcn_s_setprio(1);
        #pragma unroll
        for (int ks = 0; ks < 2; ++ks) {
            bf16x8 a = *(const bf16x8*)(h2 + (rg*16 + (lane&15))*392 + kt*64 + ks*32 + (lane>>4)*8);
            #pragma unroll
            for (int fn = 0; fn < 4; ++fn) {
                int n = ch*64 + fn*16 + (lane&15);
                int g = ks*4 + (lane>>4);
                bf16x8 b = *(const bf16x8*)(w3c + n*64 + ((g ^ (n&7)) * 8));
                acc3[fn] = __builtin_amdgcn_mfma_f32_16x16x32_bf16(a, b, acc3[fn], 0,0,0);
            }
        }
        __builtin_amdgcn_s_setprio(0);
        __syncthreads();
    }
    #pragma unroll
    for (int fn = 0; fn < 4; ++fn) {
        int col = ch*64 + fn*16 + (lane&15);
        float bb = b3[col];
        #pragma unroll
        for (int q = 0; q < 4; ++q) {
            int row = p0 + rg*16 + (lane>>4)*4 + q;
            out[(size_t)row*128 + col] = acc3[fn][q] + bb;
        }
    }
}

extern "C" void kernel_launch(void* const* d_in, const int* in_sizes, int n_in,
                              void* d_out, int out_size, void* d_ws, size_t ws_size,
                              hipStream_t stream) {
    const float* feat = (const float*)d_in[0];  // [256][768]
    const float* W1   = (const float*)d_in[1];  // [1536][768]
    const float* b1   = (const float*)d_in[2];  // [768]
    const float* W2   = (const float*)d_in[3];  // [768][384]
    const float* b2   = (const float*)d_in[4];  // [384]
    const float* W3   = (const float*)d_in[5];  // [384][128]
    const float* b3   = (const float*)d_in[6];  // [128]
    float* out = (float*)d_out;

    char* ws = (char*)d_ws;
    unsigned short* W1x = (unsigned short*)(ws + 0);        // 1536*768*2 = 2,359,296
    unsigned short* W2t = (unsigned short*)(ws + 2359296);  // 384*768*2  =   589,824
    unsigned short* W3t = (unsigned short*)(ws + 2949120);  // 128*384*2  =    98,304
    float*          AB  = (float*)        (ws + 3047424);   // 256*1536*4 = 1,572,864

    prep_k<<<1488, dim3(32,8), 0, stream>>>(W1, W2, W3, W1x, W2t, W3t);
    ab_gemm_k<<<dim3(12,4), 256, 0, stream>>>(feat, W1x, b1, AB);
    fused_k<<<255, 1024, 0, stream>>>(AB, W2t, b2, W3t, b3, out);
}

// Round 4
// 55.563 us; speedup vs baseline: 1.5599x; 1.0020x over previous
//
#include <hip/hip_runtime.h>
#include <hip/hip_bf16.h>
#include <stdint.h>

#define HID 768

typedef short bf16x8 __attribute__((ext_vector_type(8)));
typedef unsigned short ushort8_t __attribute__((ext_vector_type(8)));
typedef float f32x4 __attribute__((ext_vector_type(4)));

// packed f32x2 -> bf16x2 (compiler emits v_cvt_pk_bf16_f32)
__device__ __forceinline__ unsigned int pack2bf(float x, float y) {
    __hip_bfloat162 h = __float22bfloat162_rn(make_float2(x, y));
    return *reinterpret_cast<unsigned int*>(&h);
}
__device__ __forceinline__ unsigned short f2bf1(float x) {
    __hip_bfloat16 h = __float2bfloat16(x);
    return *reinterpret_cast<unsigned short*>(&h);
}

// async global->LDS, 16B per lane; lds dest = wave-uniform base + lane*16
__device__ __forceinline__ void gload_lds16(const void* g, void* l) {
    __builtin_amdgcn_global_load_lds(
        (const __attribute__((address_space(1))) unsigned int*)g,
        (__attribute__((address_space(3))) unsigned int*)l, 16, 0, 0);
}

// ---------------- merged transpose+cast: 4 regions, f32 [R][C] -> bf16 [C][R] ----
__global__ void prep_k(const float* __restrict__ W1,
                       const float* __restrict__ W2,
                       const float* __restrict__ W3,
                       unsigned short* __restrict__ W1x,
                       unsigned short* __restrict__ W2t,
                       unsigned short* __restrict__ W3t) {
    __shared__ float t[32][33];
    int b = blockIdx.x;
    const float* in; unsigned short* op; int R, C, bx, by;
    if (b < 576)       { in = W1;           op = W1x;           R = 768; C = 768; bx = b % 24;        by = b / 24; }
    else if (b < 1152) { in = W1 + 768*768; op = W1x + 768*768; R = 768; C = 768; bx = (b-576) % 24;  by = (b-576) / 24; }
    else if (b < 1440) { in = W2;           op = W2t;           R = 768; C = 384; bx = (b-1152) % 12; by = (b-1152) / 12; }
    else               { in = W3;           op = W3t;           R = 384; C = 128; bx = (b-1440) % 4;  by = (b-1440) / 4; }
    int c0 = bx * 32, r0 = by * 32;
    int tx = threadIdx.x, ty = threadIdx.y;   // 32 x 8
    #pragma unroll
    for (int k = 0; k < 4; ++k)
        t[ty + 8*k][tx] = in[(size_t)(r0 + ty + 8*k) * C + c0 + tx];
    __syncthreads();
    #pragma unroll
    for (int k = 0; k < 4; ++k)
        op[(size_t)(c0 + ty + 8*k) * R + r0 + tx] = f2bf1(t[tx][ty + 8*k]);
}

// ---------------- AB = feat @ W1x^T (+b1 on A half) : M=256, N=1536, K=768 ------
__launch_bounds__(256, 2)
__global__ void ab_gemm_k(const float* __restrict__ F,
                          const unsigned short* __restrict__ W,
                          const float* __restrict__ b1,
                          float* __restrict__ AB) {
    __shared__ alignas(1024) unsigned short fl[2][64*72];   // 18,432 B
    __shared__ alignas(1024) unsigned short wl[2][128*64];  // 32,768 B (swizzled)
    int tid = threadIdx.x;
    int lane = tid & 63, wid = tid >> 6;   // 4 waves
    int n0 = blockIdx.x * 128, m0 = blockIdx.y * 64;
    f32x4 acc[4][2] = {};
    float4 rf[2][2];

    #pragma unroll
    for (int s = 0; s < 4; ++s) {
        int chunk = wid*4 + s;
        int row = chunk*8 + (lane>>3);
        int cg = (lane&7) ^ (row&7);
        gload_lds16(W + (size_t)(n0 + row)*HID + cg*8, (char*)wl[0] + chunk*1024);
    }
    #pragma unroll
    for (int s = 0; s < 2; ++s) {
        int idx = tid + s*256;
        int r = idx >> 3, c8 = idx & 7;
        const float4* src = (const float4*)(F + (size_t)(m0 + r)*HID + c8*8);
        rf[s][0] = src[0]; rf[s][1] = src[1];
    }
    #pragma unroll
    for (int s = 0; s < 2; ++s) {
        int idx = tid + s*256;
        int r = idx >> 3, c8 = idx & 7;
        unsigned int us32[4] = { pack2bf(rf[s][0].x, rf[s][0].y), pack2bf(rf[s][0].z, rf[s][0].w),
                                 pack2bf(rf[s][1].x, rf[s][1].y), pack2bf(rf[s][1].z, rf[s][1].w) };
        *(ushort8_t*)(fl[0] + r*72 + c8*8) = *(ushort8_t*)us32;
    }
    __syncthreads();

    for (int t = 0; t < 12; ++t) {
        int cur = t & 1;
        if (t < 11) {
            int kk = (t+1) * 64;
            #pragma unroll
            for (int s = 0; s < 4; ++s) {
                int chunk = wid*4 + s;
                int row = chunk*8 + (lane>>3);
                int cg = (lane&7) ^ (row&7);
                gload_lds16(W + (size_t)(n0 + row)*HID + kk + cg*8, (char*)wl[cur^1] + chunk*1024);
            }
            #pragma unroll
            for (int s = 0; s < 2; ++s) {
                int idx = tid + s*256;
                int r = idx >> 3, c8 = idx & 7;
                const float4* src = (const float4*)(F + (size_t)(m0 + r)*HID + kk + c8*8);
                rf[s][0] = src[0]; rf[s][1] = src[1];
            }
        }
        __builtin_amdgcn_s_setprio(1);
        #pragma unroll
        for (int ks = 0; ks < 2; ++ks) {
            bf16x8 a[4], b[2];
            #pragma unroll
            for (int fm = 0; fm < 4; ++fm)
                a[fm] = *(const bf16x8*)(fl[cur] + (fm*16 + (lane&15))*72 + ks*32 + (lane>>4)*8);
            #pragma unroll
            for (int fn = 0; fn < 2; ++fn) {
                int n = wid*32 + fn*16 + (lane&15);
                int g = ks*4 + (lane>>4);
                b[fn] = *(const bf16x8*)(wl[cur] + n*64 + ((g ^ (n&7)) * 8));
            }
            #pragma unroll
            for (int fm = 0; fm < 4; ++fm)
                #pragma unroll
                for (int fn = 0; fn < 2; ++fn)
                    acc[fm][fn] = __builtin_amdgcn_mfma_f32_16x16x32_bf16(a[fm], b[fn], acc[fm][fn], 0,0,0);
        }
        __builtin_amdgcn_s_setprio(0);
        if (t < 11) {
            #pragma unroll
            for (int s = 0; s < 2; ++s) {
                int idx = tid + s*256;
                int r = idx >> 3, c8 = idx & 7;
                unsigned int us32[4] = { pack2bf(rf[s][0].x, rf[s][0].y), pack2bf(rf[s][0].z, rf[s][0].w),
                                         pack2bf(rf[s][1].x, rf[s][1].y), pack2bf(rf[s][1].z, rf[s][1].w) };
                *(ushort8_t*)(fl[cur^1] + r*72 + c8*8) = *(ushort8_t*)us32;
            }
        }
        __syncthreads();
    }
    #pragma unroll
    for (int fm = 0; fm < 4; ++fm)
        #pragma unroll
        for (int fn = 0; fn < 2; ++fn)
            #pragma unroll
            for (int q = 0; q < 4; ++q) {
                int row = m0 + fm*16 + (lane>>4)*4 + q;
                int col = n0 + wid*32 + fn*16 + (lane&15);
                float bias = (col < 768) ? b1[col] : 0.0f;
                AB[(size_t)row*1536 + col] = acc[fm][fn][q] + bias;
            }
}

// ---------------- fused pair MLP, 16 waves, counted-vmcnt pipeline --------------
// phase A: 2x8 wave grid (64x48 tiles); phase B: 4x4 grid (32x32 tiles)
__launch_bounds__(1024, 1)
__global__ void fused_k(const float* __restrict__ AB,            // [256][1536] f32
                        const unsigned short* __restrict__ W2t,  // [384][768] bf16
                        const float* __restrict__ b2,            // [384]
                        const unsigned short* __restrict__ W3t,  // [128][384] bf16
                        const float* __restrict__ b3,            // [128]
                        float* __restrict__ out) {               // [32640][128] f32
    __shared__ alignas(1024) char smem[135168];
    unsigned short* h1b = (unsigned short*)(smem);            // 2 x [128][72]   (36,864 B)
    unsigned short* w2b = (unsigned short*)(smem + 36864);    // 2 x [384][64] swizzled (98,304 B)
    unsigned short* h2  = (unsigned short*)(smem);            // [128][392] phase B (100,352 B)
    unsigned short* w3b = (unsigned short*)(smem + 100352);   // 2 x [128][64] swizzled (32,768 B)

    int tid = threadIdx.x;
    int lane = tid & 63, wid = tid >> 6;   // 16 waves
    int wr = wid >> 3, wc = wid & 7;       // phase A: 2 x 8 wave grid
    int p0 = blockIdx.x * 128;

    // per-thread pair indices for my h1-gen row (8 threads per row)
    int hr = tid >> 3;                     // 0..127
    int hc = (tid & 7) * 8;                // col chunk within 64
    int p = p0 + hr;
    float sdisc = sqrtf((float)(511*511 - 8*p));
    int i_me = (int)((511.0f - sdisc) * 0.5f);
    if (i_me < 0) i_me = 0; if (i_me > 254) i_me = 254;
    while (i_me < 255 && (i_me+1)*255 - (i_me+1)*i_me/2 <= p) ++i_me;
    while (i_me > 0 && i_me*255 - i_me*(i_me-1)/2 > p) --i_me;
    int j_me = i_me + 1 + (p - (i_me*255 - i_me*(i_me-1)/2));

    float4 ra[2], rb[2];

    // ---- prologue: AB(0) regs first, then w2(0) gloads (order matters for vmcnt)
    {
        const float4* pa = (const float4*)(AB + (size_t)i_me*1536 + hc);
        const float4* pb = (const float4*)(AB + (size_t)j_me*1536 + 768 + hc);
        ra[0] = pa[0]; ra[1] = pa[1]; rb[0] = pb[0]; rb[1] = pb[1];
    }
    #pragma unroll
    for (int s = 0; s < 3; ++s) {
        int chunk = wid*3 + s;                 // 48 chunks of 1024B
        int row = chunk*8 + (lane>>3);
        int cg = (lane&7) ^ (row&7);
        gload_lds16(W2t + (size_t)row*HID + cg*8, (char*)w2b + chunk*1024);
    }
    {
        unsigned int us32[4];
        #pragma unroll
        for (int u = 0; u < 2; ++u) {
            us32[u*2+0] = pack2bf(fmaxf(ra[u].x + rb[u].x, 0.f), fmaxf(ra[u].y + rb[u].y, 0.f));
            us32[u*2+1] = pack2bf(fmaxf(ra[u].z + rb[u].z, 0.f), fmaxf(ra[u].w + rb[u].w, 0.f));
        }
        *(ushort8_t*)(h1b + hr*72 + hc) = *(ushort8_t*)us32;
    }
    asm volatile("s_waitcnt lgkmcnt(0)" ::: "memory");
    __builtin_amdgcn_sched_barrier(0);
    __builtin_amdgcn_s_barrier();          // w2(0) gloads still in flight

    f32x4 acc2[4][3] = {};
    for (int t = 0; t < 11; ++t) {
        int cur = t & 1;
        unsigned short* h1c = h1b + cur * (128*72);
        unsigned short* w2c = w2b + cur * (384*64);
        unsigned short* h1n = h1b + (cur^1) * (128*72);
        unsigned short* w2n = w2b + (cur^1) * (384*64);
        int kk = (t+1) * 64;
        // issue AB(t+1) reg loads (older), then w2(t+1) gloads (newer)
        {
            const float4* pa = (const float4*)(AB + (size_t)i_me*1536 + kk + hc);
            const float4* pb = (const float4*)(AB + (size_t)j_me*1536 + 768 + kk + hc);
            ra[0] = pa[0]; ra[1] = pa[1]; rb[0] = pb[0]; rb[1] = pb[1];
        }
        #pragma unroll
        for (int s = 0; s < 3; ++s) {
            int chunk = wid*3 + s;
            int row = chunk*8 + (lane>>3);
            int cg = (lane&7) ^ (row&7);
            gload_lds16(W2t + (size_t)row*HID + kk + cg*8, (char*)w2n + chunk*1024);
        }
        // outstanding: 3 w2(t) + 4 AB(t+1) + 3 w2(t+1) = 10 -> complete oldest 3 = w2(t)
        asm volatile("s_waitcnt vmcnt(7)" ::: "memory");
        __builtin_amdgcn_sched_barrier(0);
        __builtin_amdgcn_s_setprio(1);
        #pragma unroll
        for (int ks = 0; ks < 2; ++ks) {
            bf16x8 a[4], b[3];
            #pragma unroll
            for (int fm = 0; fm < 4; ++fm)
                a[fm] = *(const bf16x8*)(h1c + (wr*64 + fm*16 + (lane&15))*72 + ks*32 + (lane>>4)*8);
            #pragma unroll
            for (int fn = 0; fn < 3; ++fn) {
                int n = wc*48 + fn*16 + (lane&15);
                int g = ks*4 + (lane>>4);
                b[fn] = *(const bf16x8*)(w2c + n*64 + ((g ^ (n&7)) * 8));
            }
            #pragma unroll
            for (int fm = 0; fm < 4; ++fm)
                #pragma unroll
                for (int fn = 0; fn < 3; ++fn)
                    acc2[fm][fn] = __builtin_amdgcn_mfma_f32_16x16x32_bf16(a[fm], b[fn], acc2[fm][fn], 0,0,0);
        }
        __builtin_amdgcn_s_setprio(0);
        {   // h1(t+1) write: compiler waits only the 4 AB loads (w2(t+1) stays in flight)
            unsigned int us32[4];
            #pragma unroll
            for (int u = 0; u < 2; ++u) {
                us32[u*2+0] = pack2bf(fmaxf(ra[u].x + rb[u].x, 0.f), fmaxf(ra[u].y + rb[u].y, 0.f));
                us32[u*2+1] = pack2bf(fmaxf(ra[u].z + rb[u].z, 0.f), fmaxf(ra[u].w + rb[u].w, 0.f));
            }
            *(ushort8_t*)(h1n + hr*72 + hc) = *(ushort8_t*)us32;
        }
        asm volatile("s_waitcnt lgkmcnt(0)" ::: "memory");
        __builtin_amdgcn_sched_barrier(0);
        __builtin_amdgcn_s_barrier();
    }
    {   // tail step t=11
        unsigned short* h1c = h1b + (11&1) * (128*72);
        unsigned short* w2c = w2b + (11&1) * (384*64);
        asm volatile("s_waitcnt vmcnt(0)" ::: "memory");
        __builtin_amdgcn_sched_barrier(0);
        __builtin_amdgcn_s_setprio(1);
        #pragma unroll
        for (int ks = 0; ks < 2; ++ks) {
            bf16x8 a[4], b[3];
            #pragma unroll
            for (int fm = 0; fm < 4; ++fm)
                a[fm] = *(const bf16x8*)(h1c + (wr*64 + fm*16 + (lane&15))*72 + ks*32 + (lane>>4)*8);
            #pragma unroll
            for (int fn = 0; fn < 3; ++fn) {
                int n = wc*48 + fn*16 + (lane&15);
                int g = ks*4 + (lane>>4);
                b[fn] = *(const bf16x8*)(w2c + n*64 + ((g ^ (n&7)) * 8));
            }
            #pragma unroll
            for (int fm = 0; fm < 4; ++fm)
                #pragma unroll
                for (int fn = 0; fn < 3; ++fn)
                    acc2[fm][fn] = __builtin_amdgcn_mfma_f32_16x16x32_bf16(a[fm], b[fn], acc2[fm][fn], 0,0,0);
        }
        __builtin_amdgcn_s_setprio(0);
        __builtin_amdgcn_s_barrier();      // all reads of h1/w2 done -> smem reusable
    }

    // h2 = relu(acc2 + b2) -> LDS [128][392]
    #pragma unroll
    for (int fn = 0; fn < 3; ++fn) {
        int col = wc*48 + fn*16 + (lane&15);
        float bb = b2[col];
        #pragma unroll
        for (int fm = 0; fm < 4; ++fm)
            #pragma unroll
            for (int q = 0; q < 4; ++q) {
                int row = wr*64 + fm*16 + (lane>>4)*4 + q;
                h2[row*392 + col] = f2bf1(fmaxf(acc2[fm][fn][q] + bb, 0.f));
            }
    }
    {   // stage w3 kt=0 (16 chunks, 1 per wave)
        int chunk = wid;
        int row = chunk*8 + (lane>>3);
        int cg = (lane&7) ^ (row&7);
        gload_lds16(W3t + (size_t)row*384 + cg*8, (char*)w3b + chunk*1024);
    }
    __syncthreads();

    // phase B: 4x4 wave grid, wave tile 32 rows x 32 cols
    int wrB = wid >> 2, wcB = wid & 3;
    f32x4 acc3[2][2] = {};
    for (int kt = 0; kt < 6; ++kt) {
        int cur = kt & 1;
        unsigned short* w3c = w3b + cur * (128*64);
        if (kt < 5) {
            unsigned short* w3n = w3b + (cur^1) * (128*64);
            int chunk = wid;
            int row = chunk*8 + (lane>>3);
            int cg = (lane&7) ^ (row&7);
            gload_lds16(W3t + (size_t)row*384 + (kt+1)*64 + cg*8, (char*)w3n + chunk*1024);
        }
        __builtin_amdgcn_s_setprio(1);
        #pragma unroll
        for (int ks = 0; ks < 2; ++ks) {
            bf16x8 a[2], b[2];
            #pragma unroll
            for (int fm = 0; fm < 2; ++fm)
                a[fm] = *(const bf16x8*)(h2 + (wrB*32 + fm*16 + (lane&15))*392 + kt*64 + ks*32 + (lane>>4)*8);
            #pragma unroll
            for (int fn = 0; fn < 2; ++fn) {
                int n = wcB*32 + fn*16 + (lane&15);
                int g = ks*4 + (lane>>4);
                b[fn] = *(const bf16x8*)(w3c + n*64 + ((g ^ (n&7)) * 8));
            }
            #pragma unroll
            for (int fm = 0; fm < 2; ++fm)
                #pragma unroll
                for (int fn = 0; fn < 2; ++fn)
                    acc3[fm][fn] = __builtin_amdgcn_mfma_f32_16x16x32_bf16(a[fm], b[fn], acc3[fm][fn], 0,0,0);
        }
        __builtin_amdgcn_s_setprio(0);
        __syncthreads();
    }
    #pragma unroll
    for (int fm = 0; fm < 2; ++fm)
        #pragma unroll
        for (int fn = 0; fn < 2; ++fn) {
            int col = wcB*32 + fn*16 + (lane&15);
            float bb = b3[col];
            #pragma unroll
            for (int q = 0; q < 4; ++q) {
                int row = p0 + wrB*32 + fm*16 + (lane>>4)*4 + q;
                out[(size_t)row*128 + col] = acc3[fm][fn][q] + bb;
            }
        }
}

extern "C" void kernel_launch(void* const* d_in, const int* in_sizes, int n_in,
                              void* d_out, int out_size, void* d_ws, size_t ws_size,
                              hipStream_t stream) {
    const float* feat = (const float*)d_in[0];  // [256][768]
    const float* W1   = (const float*)d_in[1];  // [1536][768]
    const float* b1   = (const float*)d_in[2];  // [768]
    const float* W2   = (const float*)d_in[3];  // [768][384]
    const float* b2   = (const float*)d_in[4];  // [384]
    const float* W3   = (const float*)d_in[5];  // [384][128]
    const float* b3   = (const float*)d_in[6];  // [128]
    float* out = (float*)d_out;

    char* ws = (char*)d_ws;
    unsigned short* W1x = (unsigned short*)(ws + 0);        // 1536*768*2 = 2,359,296
    unsigned short* W2t = (unsigned short*)(ws + 2359296);  // 384*768*2  =   589,824
    unsigned short* W3t = (unsigned short*)(ws + 2949120);  // 128*384*2  =    98,304
    float*          AB  = (float*)        (ws + 3047424);   // 256*1536*4 = 1,572,864

    prep_k<<<1488, dim3(32,8), 0, stream>>>(W1, W2, W3, W1x, W2t, W3t);
    ab_gemm_k<<<dim3(12,4), 256, 0, stream>>>(feat, W1x, b1, AB);
    fused_k<<<255, 1024, 0, stream>>>(AB, W2t, b2, W3t, b3, out);
}

// Round 5
// 53.268 us; speedup vs baseline: 1.6270x; 1.0431x over previous
//
#include <hip/hip_runtime.h>
#include <hip/hip_bf16.h>
#include <stdint.h>

#define HID 768

typedef short bf16x8 __attribute__((ext_vector_type(8)));
typedef unsigned short ushort8_t __attribute__((ext_vector_type(8)));
typedef float f32x4 __attribute__((ext_vector_type(4)));

// packed f32x2 -> bf16x2 (compiler emits v_cvt_pk_bf16_f32)
__device__ __forceinline__ unsigned int pack2bf(float x, float y) {
    __hip_bfloat162 h = __float22bfloat162_rn(make_float2(x, y));
    return *reinterpret_cast<unsigned int*>(&h);
}
__device__ __forceinline__ unsigned short f2bf1(float x) {
    __hip_bfloat16 h = __float2bfloat16(x);
    return *reinterpret_cast<unsigned short*>(&h);
}

// async global->LDS, 16B per lane; lds dest = wave-uniform base + lane*16
__device__ __forceinline__ void gload_lds16(const void* g, void* l) {
    __builtin_amdgcn_global_load_lds(
        (const __attribute__((address_space(1))) unsigned int*)g,
        (__attribute__((address_space(3))) unsigned int*)l, 16, 0, 0);
}

// ---------------- merged transpose+cast: 4 regions, f32 [R][C] -> bf16 [C][R] ----
__global__ void prep_k(const float* __restrict__ W1,
                       const float* __restrict__ W2,
                       const float* __restrict__ W3,
                       unsigned short* __restrict__ W1x,
                       unsigned short* __restrict__ W2t,
                       unsigned short* __restrict__ W3t) {
    __shared__ float t[32][33];
    int b = blockIdx.x;
    const float* in; unsigned short* op; int R, C, bx, by;
    if (b < 576)       { in = W1;           op = W1x;           R = 768; C = 768; bx = b % 24;        by = b / 24; }
    else if (b < 1152) { in = W1 + 768*768; op = W1x + 768*768; R = 768; C = 768; bx = (b-576) % 24;  by = (b-576) / 24; }
    else if (b < 1440) { in = W2;           op = W2t;           R = 768; C = 384; bx = (b-1152) % 12; by = (b-1152) / 12; }
    else               { in = W3;           op = W3t;           R = 384; C = 128; bx = (b-1440) % 4;  by = (b-1440) / 4; }
    int c0 = bx * 32, r0 = by * 32;
    int tx = threadIdx.x, ty = threadIdx.y;   // 32 x 8
    #pragma unroll
    for (int k = 0; k < 4; ++k)
        t[ty + 8*k][tx] = in[(size_t)(r0 + ty + 8*k) * C + c0 + tx];
    __syncthreads();
    #pragma unroll
    for (int k = 0; k < 4; ++k)
        op[(size_t)(c0 + ty + 8*k) * R + r0 + tx] = f2bf1(t[tx][ty + 8*k]);
}

// ---------------- AB = feat @ W1x^T (+b1 on A half) : M=256, N=1536, K=768 ------
// 96 blocks of 64m x 64n; 4 waves, wave n-band = wid*16
__launch_bounds__(256, 2)
__global__ void ab_gemm_k(const float* __restrict__ F,
                          const unsigned short* __restrict__ W,
                          const float* __restrict__ b1,
                          float* __restrict__ AB) {
    __shared__ alignas(1024) unsigned short fl[2][64*72];   // 18,432 B
    __shared__ alignas(1024) unsigned short wl[2][64*64];   // 16,384 B (swizzled)
    int tid = threadIdx.x;
    int lane = tid & 63, wid = tid >> 6;   // 4 waves
    int n0 = blockIdx.x * 64, m0 = blockIdx.y * 64;
    f32x4 acc[4] = {};
    float4 rf[2][2];

    #pragma unroll
    for (int s = 0; s < 2; ++s) {          // W tile 64x64 -> 8 chunks of 1024B
        int chunk = wid*2 + s;
        int row = chunk*8 + (lane>>3);
        int cg = (lane&7) ^ (row&7);
        gload_lds16(W + (size_t)(n0 + row)*HID + cg*8, (char*)wl[0] + chunk*1024);
    }
    #pragma unroll
    for (int s = 0; s < 2; ++s) {          // F tile 64x64 f32
        int idx = tid + s*256;
        int r = idx >> 3, c8 = idx & 7;
        const float4* src = (const float4*)(F + (size_t)(m0 + r)*HID + c8*8);
        rf[s][0] = src[0]; rf[s][1] = src[1];
    }
    #pragma unroll
    for (int s = 0; s < 2; ++s) {
        int idx = tid + s*256;
        int r = idx >> 3, c8 = idx & 7;
        unsigned int us32[4] = { pack2bf(rf[s][0].x, rf[s][0].y), pack2bf(rf[s][0].z, rf[s][0].w),
                                 pack2bf(rf[s][1].x, rf[s][1].y), pack2bf(rf[s][1].z, rf[s][1].w) };
        *(ushort8_t*)(fl[0] + r*72 + c8*8) = *(ushort8_t*)us32;
    }
    __syncthreads();

    for (int t = 0; t < 12; ++t) {
        int cur = t & 1;
        if (t < 11) {
            int kk = (t+1) * 64;
            #pragma unroll
            for (int s = 0; s < 2; ++s) {
                int chunk = wid*2 + s;
                int row = chunk*8 + (lane>>3);
                int cg = (lane&7) ^ (row&7);
                gload_lds16(W + (size_t)(n0 + row)*HID + kk + cg*8, (char*)wl[cur^1] + chunk*1024);
            }
            #pragma unroll
            for (int s = 0; s < 2; ++s) {
                int idx = tid + s*256;
                int r = idx >> 3, c8 = idx & 7;
                const float4* src = (const float4*)(F + (size_t)(m0 + r)*HID + kk + c8*8);
                rf[s][0] = src[0]; rf[s][1] = src[1];
            }
        }
        __builtin_amdgcn_s_setprio(1);
        #pragma unroll
        for (int ks = 0; ks < 2; ++ks) {
            bf16x8 a[4], b;
            #pragma unroll
            for (int fm = 0; fm < 4; ++fm)
                a[fm] = *(const bf16x8*)(fl[cur] + (fm*16 + (lane&15))*72 + ks*32 + (lane>>4)*8);
            {
                int n = wid*16 + (lane&15);
                int g = ks*4 + (lane>>4);
                b = *(const bf16x8*)(wl[cur] + n*64 + ((g ^ (n&7)) * 8));
            }
            #pragma unroll
            for (int fm = 0; fm < 4; ++fm)
                acc[fm] = __builtin_amdgcn_mfma_f32_16x16x32_bf16(a[fm], b, acc[fm], 0,0,0);
        }
        __builtin_amdgcn_s_setprio(0);
        if (t < 11) {
            #pragma unroll
            for (int s = 0; s < 2; ++s) {
                int idx = tid + s*256;
                int r = idx >> 3, c8 = idx & 7;
                unsigned int us32[4] = { pack2bf(rf[s][0].x, rf[s][0].y), pack2bf(rf[s][0].z, rf[s][0].w),
                                         pack2bf(rf[s][1].x, rf[s][1].y), pack2bf(rf[s][1].z, rf[s][1].w) };
                *(ushort8_t*)(fl[cur^1] + r*72 + c8*8) = *(ushort8_t*)us32;
            }
        }
        __syncthreads();
    }
    #pragma unroll
    for (int fm = 0; fm < 4; ++fm)
        #pragma unroll
        for (int q = 0; q < 4; ++q) {
            int row = m0 + fm*16 + (lane>>4)*4 + q;
            int col = n0 + wid*16 + (lane&15);
            float bias = (col < 768) ? b1[col] : 0.0f;
            AB[(size_t)row*1536 + col] = acc[fm][q] + bias;
        }
}

// ---------------- fused pair MLP, 16 waves, sub-phase-split pipeline ------------
// phase A: 2x8 wave grid (64x48 tiles), K-step split into ks0 | mid-bar | ks1
__launch_bounds__(1024, 1)
__global__ void fused_k(const float* __restrict__ AB,            // [256][1536] f32
                        const unsigned short* __restrict__ W2t,  // [384][768] bf16
                        const float* __restrict__ b2,            // [384]
                        const unsigned short* __restrict__ W3t,  // [128][384] bf16
                        const float* __restrict__ b3,            // [128]
                        float* __restrict__ out) {               // [32640][128] f32
    __shared__ alignas(1024) char smem[135168];
    unsigned short* h1b = (unsigned short*)(smem);            // 2 x [128][72]   (36,864 B)
    unsigned short* w2b = (unsigned short*)(smem + 36864);    // 2 x [384][64] swizzled (98,304 B)
    unsigned short* h2  = (unsigned short*)(smem);            // [128][392] phase B (100,352 B)
    unsigned short* w3b = (unsigned short*)(smem + 100352);   // 2 x [128][64] swizzled (32,768 B)

    int tid = threadIdx.x;
    int lane = tid & 63, wid = tid >> 6;   // 16 waves
    int wr = wid >> 3, wc = wid & 7;       // phase A: 2 x 8 wave grid
    int p0 = blockIdx.x * 128;

    // per-thread pair indices for my h1-gen row (8 threads per row)
    int hr = tid >> 3;                     // 0..127
    int hc = (tid & 7) * 8;                // col chunk within 64
    int p = p0 + hr;
    float sdisc = sqrtf((float)(511*511 - 8*p));
    int i_me = (int)((511.0f - sdisc) * 0.5f);
    if (i_me < 0) i_me = 0; if (i_me > 254) i_me = 254;
    while (i_me < 255 && (i_me+1)*255 - (i_me+1)*i_me/2 <= p) ++i_me;
    while (i_me > 0 && i_me*255 - i_me*(i_me-1)/2 > p) --i_me;
    int j_me = i_me + 1 + (p - (i_me*255 - i_me*(i_me-1)/2));

    float4 ra[2], rb[2];

    // ---- prologue: h1(0) via regs, then w2(0) gloads
    {
        const float4* pa = (const float4*)(AB + (size_t)i_me*1536 + hc);
        const float4* pb = (const float4*)(AB + (size_t)j_me*1536 + 768 + hc);
        ra[0] = pa[0]; ra[1] = pa[1]; rb[0] = pb[0]; rb[1] = pb[1];
        unsigned int us32[4];
        #pragma unroll
        for (int u = 0; u < 2; ++u) {
            us32[u*2+0] = pack2bf(fmaxf(ra[u].x + rb[u].x, 0.f), fmaxf(ra[u].y + rb[u].y, 0.f));
            us32[u*2+1] = pack2bf(fmaxf(ra[u].z + rb[u].z, 0.f), fmaxf(ra[u].w + rb[u].w, 0.f));
        }
        *(ushort8_t*)(h1b + hr*72 + hc) = *(ushort8_t*)us32;
    }
    #pragma unroll
    for (int s = 0; s < 3; ++s) {
        int chunk = wid*3 + s;                 // 48 chunks of 1024B
        int row = chunk*8 + (lane>>3);
        int cg = (lane&7) ^ (row&7);
        gload_lds16(W2t + (size_t)row*HID + cg*8, (char*)w2b + chunk*1024);
    }
    asm volatile("s_waitcnt lgkmcnt(0)" ::: "memory");
    __builtin_amdgcn_sched_barrier(0);
    __builtin_amdgcn_s_barrier();          // w2(0) gloads still in flight

    f32x4 acc2[4][3] = {};
    for (int t = 0; t < 11; ++t) {
        int cur = t & 1;
        unsigned short* h1c = h1b + cur * (128*72);
        unsigned short* w2c = w2b + cur * (384*64);
        unsigned short* h1n = h1b + (cur^1) * (128*72);
        unsigned short* w2n = w2b + (cur^1) * (384*64);
        int kk = (t+1) * 64;

        // ---- sub-phase ks0: AB(t+1) loads + ks0 MFMA ----
        {
            const float4* pa = (const float4*)(AB + (size_t)i_me*1536 + kk + hc);
            const float4* pb = (const float4*)(AB + (size_t)j_me*1536 + 768 + kk + hc);
            ra[0] = pa[0]; ra[1] = pa[1]; rb[0] = pb[0]; rb[1] = pb[1];
        }
        // outstanding: 3 w2(t) (oldest) + 4 AB(t+1) -> complete w2(t) only
        asm volatile("s_waitcnt vmcnt(4)" ::: "memory");
        __builtin_amdgcn_sched_barrier(0);
        __builtin_amdgcn_s_setprio(1);
        {
            bf16x8 a[4], b[3];
            #pragma unroll
            for (int fm = 0; fm < 4; ++fm)
                a[fm] = *(const bf16x8*)(h1c + (wr*64 + fm*16 + (lane&15))*72 + (lane>>4)*8);
            #pragma unroll
            for (int fn = 0; fn < 3; ++fn) {
                int n = wc*48 + fn*16 + (lane&15);
                int g = (lane>>4);
                b[fn] = *(const bf16x8*)(w2c + n*64 + ((g ^ (n&7)) * 8));
            }
            #pragma unroll
            for (int fm = 0; fm < 4; ++fm)
                #pragma unroll
                for (int fn = 0; fn < 3; ++fn)
                    acc2[fm][fn] = __builtin_amdgcn_mfma_f32_16x16x32_bf16(a[fm], b[fn], acc2[fm][fn], 0,0,0);
        }
        __builtin_amdgcn_s_setprio(0);
        __builtin_amdgcn_sched_barrier(0);
        __builtin_amdgcn_s_barrier();      // mid-barrier: de-convoy LDS bursts

        // ---- sub-phase ks1: w2(t+1) gloads + ks1 MFMA + h1(t+1) write ----
        #pragma unroll
        for (int s = 0; s < 3; ++s) {
            int chunk = wid*3 + s;
            int row = chunk*8 + (lane>>3);
            int cg = (lane&7) ^ (row&7);
            gload_lds16(W2t + (size_t)row*HID + kk + cg*8, (char*)w2n + chunk*1024);
        }
        __builtin_amdgcn_s_setprio(1);
        {
            bf16x8 a[4], b[3];
            #pragma unroll
            for (int fm = 0; fm < 4; ++fm)
                a[fm] = *(const bf16x8*)(h1c + (wr*64 + fm*16 + (lane&15))*72 + 32 + (lane>>4)*8);
            #pragma unroll
            for (int fn = 0; fn < 3; ++fn) {
                int n = wc*48 + fn*16 + (lane&15);
                int g = 4 + (lane>>4);
                b[fn] = *(const bf16x8*)(w2c + n*64 + ((g ^ (n&7)) * 8));
            }
            #pragma unroll
            for (int fm = 0; fm < 4; ++fm)
                #pragma unroll
                for (int fn = 0; fn < 3; ++fn)
                    acc2[fm][fn] = __builtin_amdgcn_mfma_f32_16x16x32_bf16(a[fm], b[fn], acc2[fm][fn], 0,0,0);
        }
        __builtin_amdgcn_s_setprio(0);
        {   // h1(t+1) write: compiler waits only the 4 AB loads
            unsigned int us32[4];
            #pragma unroll
            for (int u = 0; u < 2; ++u) {
                us32[u*2+0] = pack2bf(fmaxf(ra[u].x + rb[u].x, 0.f), fmaxf(ra[u].y + rb[u].y, 0.f));
                us32[u*2+1] = pack2bf(fmaxf(ra[u].z + rb[u].z, 0.f), fmaxf(ra[u].w + rb[u].w, 0.f));
            }
            *(ushort8_t*)(h1n + hr*72 + hc) = *(ushort8_t*)us32;
        }
        asm volatile("s_waitcnt lgkmcnt(0)" ::: "memory");
        __builtin_amdgcn_sched_barrier(0);
        __builtin_amdgcn_s_barrier();
    }
    {   // tail step t=11
        unsigned short* h1c = h1b + (11&1) * (128*72);
        unsigned short* w2c = w2b + (11&1) * (384*64);
        asm volatile("s_waitcnt vmcnt(0)" ::: "memory");
        __builtin_amdgcn_sched_barrier(0);
        __builtin_amdgcn_s_setprio(1);
        #pragma unroll
        for (int ks = 0; ks < 2; ++ks) {
            bf16x8 a[4], b[3];
            #pragma unroll
            for (int fm = 0; fm < 4; ++fm)
                a[fm] = *(const bf16x8*)(h1c + (wr*64 + fm*16 + (lane&15))*72 + ks*32 + (lane>>4)*8);
            #pragma unroll
            for (int fn = 0; fn < 3; ++fn) {
                int n = wc*48 + fn*16 + (lane&15);
                int g = ks*4 + (lane>>4);
                b[fn] = *(const bf16x8*)(w2c + n*64 + ((g ^ (n&7)) * 8));
            }
            #pragma unroll
            for (int fm = 0; fm < 4; ++fm)
                #pragma unroll
                for (int fn = 0; fn < 3; ++fn)
                    acc2[fm][fn] = __builtin_amdgcn_mfma_f32_16x16x32_bf16(a[fm], b[fn], acc2[fm][fn], 0,0,0);
        }
        __builtin_amdgcn_s_setprio(0);
        __builtin_amdgcn_s_barrier();      // all reads of h1/w2 done -> smem reusable
    }

    // h2 = relu(acc2 + b2) -> LDS [128][392]
    #pragma unroll
    for (int fn = 0; fn < 3; ++fn) {
        int col = wc*48 + fn*16 + (lane&15);
        float bb = b2[col];
        #pragma unroll
        for (int fm = 0; fm < 4; ++fm)
            #pragma unroll
            for (int q = 0; q < 4; ++q) {
                int row = wr*64 + fm*16 + (lane>>4)*4 + q;
                h2[row*392 + col] = f2bf1(fmaxf(acc2[fm][fn][q] + bb, 0.f));
            }
    }
    {   // stage w3 kt=0 (16 chunks, 1 per wave)
        int chunk = wid;
        int row = chunk*8 + (lane>>3);
        int cg = (lane&7) ^ (row&7);
        gload_lds16(W3t + (size_t)row*384 + cg*8, (char*)w3b + chunk*1024);
    }
    __syncthreads();

    // phase B: 4x4 wave grid, wave tile 32 rows x 32 cols
    int wrB = wid >> 2, wcB = wid & 3;
    f32x4 acc3[2][2] = {};
    for (int kt = 0; kt < 6; ++kt) {
        int cur = kt & 1;
        unsigned short* w3c = w3b + cur * (128*64);
        if (kt < 5) {
            unsigned short* w3n = w3b + (cur^1) * (128*64);
            int chunk = wid;
            int row = chunk*8 + (lane>>3);
            int cg = (lane&7) ^ (row&7);
            gload_lds16(W3t + (size_t)row*384 + (kt+1)*64 + cg*8, (char*)w3n + chunk*1024);
        }
        __builtin_amdgcn_s_setprio(1);
        #pragma unroll
        for (int ks = 0; ks < 2; ++ks) {
            bf16x8 a[2], b[2];
            #pragma unroll
            for (int fm = 0; fm < 2; ++fm)
                a[fm] = *(const bf16x8*)(h2 + (wrB*32 + fm*16 + (lane&15))*392 + kt*64 + ks*32 + (lane>>4)*8);
            #pragma unroll
            for (int fn = 0; fn < 2; ++fn) {
                int n = wcB*32 + fn*16 + (lane&15);
                int g = ks*4 + (lane>>4);
                b[fn] = *(const bf16x8*)(w3c + n*64 + ((g ^ (n&7)) * 8));
            }
            #pragma unroll
            for (int fm = 0; fm < 2; ++fm)
                #pragma unroll
                for (int fn = 0; fn < 2; ++fn)
                    acc3[fm][fn] = __builtin_amdgcn_mfma_f32_16x16x32_bf16(a[fm], b[fn], acc3[fm][fn], 0,0,0);
        }
        __builtin_amdgcn_s_setprio(0);
        __syncthreads();
    }
    #pragma unroll
    for (int fm = 0; fm < 2; ++fm)
        #pragma unroll
        for (int fn = 0; fn < 2; ++fn) {
            int col = wcB*32 + fn*16 + (lane&15);
            float bb = b3[col];
            #pragma unroll
            for (int q = 0; q < 4; ++q) {
                int row = p0 + wrB*32 + fm*16 + (lane>>4)*4 + q;
                out[(size_t)row*128 + col] = acc3[fm][fn][q] + bb;
            }
        }
}

extern "C" void kernel_launch(void* const* d_in, const int* in_sizes, int n_in,
                              void* d_out, int out_size, void* d_ws, size_t ws_size,
                              hipStream_t stream) {
    const float* feat = (const float*)d_in[0];  // [256][768]
    const float* W1   = (const float*)d_in[1];  // [1536][768]
    const float* b1   = (const float*)d_in[2];  // [768]
    const float* W2   = (const float*)d_in[3];  // [768][384]
    const float* b2   = (const float*)d_in[4];  // [384]
    const float* W3   = (const float*)d_in[5];  // [384][128]
    const float* b3   = (const float*)d_in[6];  // [128]
    float* out = (float*)d_out;

    char* ws = (char*)d_ws;
    unsigned short* W1x = (unsigned short*)(ws + 0);        // 1536*768*2 = 2,359,296
    unsigned short* W2t = (unsigned short*)(ws + 2359296);  // 384*768*2  =   589,824
    unsigned short* W3t = (unsigned short*)(ws + 2949120);  // 128*384*2  =    98,304
    float*          AB  = (float*)        (ws + 3047424);   // 256*1536*4 = 1,572,864

    prep_k<<<1488, dim3(32,8), 0, stream>>>(W1, W2, W3, W1x, W2t, W3t);
    ab_gemm_k<<<dim3(24,4), 256, 0, stream>>>(feat, W1x, b1, AB);
    fused_k<<<255, 1024, 0, stream>>>(AB, W2t, b2, W3t, b3, out);
}